// Round 1
// baseline (83.687 us; speedup 1.0000x reference)
//
#include <hip/hip_runtime.h>
#include <hip/hip_bf16.h>

// Leave-one-out Gaussian-kernel regression (Nadaraya-Watson), N=4096, D_IN=4, D_OUT=3.
// out[i,c] = (sum_{j!=i} K_ji_c * Y[j,c]) / (sum_{j!=i} K_ji_c)
// K_ji_c = exp(-0.5*((Ft[j,c]-Fx[i,c])/h)^2),  Fx = x@W^T, Ft = train_X@W^T.

constexpr int TI  = 8;    // query points per block
constexpr int BLK = 256;  // threads per block

// Kernel 1: project x and train_X through W (3x4). F layout: Fx[N*3] then Ft[N*3].
__global__ void proj_kernel(const float* __restrict__ x,
                            const float* __restrict__ tX,
                            const float* __restrict__ W,
                            float* __restrict__ F, int N) {
    int t = blockIdx.x * blockDim.x + threadIdx.x;
    if (t >= 2 * N) return;
    const float* src = (t < N) ? x : tX;
    int row = (t < N) ? t : t - N;
    float4 v = ((const float4*)src)[row];  // D_IN = 4, 16B aligned
#pragma unroll
    for (int c = 0; c < 3; ++c) {
        float s = v.x * W[c * 4 + 0] + v.y * W[c * 4 + 1] +
                  v.z * W[c * 4 + 2] + v.w * W[c * 4 + 3];
        F[t * 3 + c] = s;  // t<N -> Fx region; t>=N -> Ft region (contiguous)
    }
}

// Kernel 2: main KDE accumulation.
__global__ __launch_bounds__(BLK) void kde_main(const float* __restrict__ F,
                                                const float* __restrict__ Y,
                                                const float* __restrict__ hptr,
                                                float* __restrict__ out, int N) {
    const float* Fx = F;
    const float* Ft = F + 3 * N;
    const int i0  = blockIdx.x * TI;
    const int tid = threadIdx.x;

    const float h = hptr[0];
    // exp(-0.5*d^2/h^2) = exp2( (-0.5*log2(e)/h^2) * d^2 )
    const float scale = -0.72134752044448170368f / (h * h);

    // Fx for this block's TI points (broadcast loads, L1/L2 hit)
    float fx[TI][3];
#pragma unroll
    for (int a = 0; a < TI; ++a)
#pragma unroll
        for (int c = 0; c < 3; ++c) fx[a][c] = Fx[(i0 + a) * 3 + c];

    float num[TI][3], den[TI][3];
#pragma unroll
    for (int a = 0; a < TI; ++a)
#pragma unroll
        for (int c = 0; c < 3; ++c) { num[a][c] = 0.f; den[a][c] = 0.f; }

    for (int j = tid; j < N; j += BLK) {
        const float ft0 = Ft[3 * j + 0];
        const float ft1 = Ft[3 * j + 1];
        const float ft2 = Ft[3 * j + 2];
        const float y0  = Y[3 * j + 0];
        const float y1  = Y[3 * j + 1];
        const float y2  = Y[3 * j + 2];
#pragma unroll
        for (int a = 0; a < TI; ++a) {
            float d0 = ft0 - fx[a][0];
            float d1 = ft1 - fx[a][1];
            float d2 = ft2 - fx[a][2];
            float k0 = exp2f(scale * d0 * d0);
            float k1 = exp2f(scale * d1 * d1);
            float k2 = exp2f(scale * d2 * d2);
            den[a][0] += k0; num[a][0] = fmaf(k0, y0, num[a][0]);
            den[a][1] += k1; num[a][1] = fmaf(k1, y1, num[a][1]);
            den[a][2] += k2; num[a][2] = fmaf(k2, y2, num[a][2]);
        }
    }

    // Wave-level butterfly reduction (wave = 64 lanes on gfx950)
#pragma unroll
    for (int a = 0; a < TI; ++a)
#pragma unroll
        for (int c = 0; c < 3; ++c) {
            float n_ = num[a][c], d_ = den[a][c];
#pragma unroll
            for (int off = 32; off > 0; off >>= 1) {
                n_ += __shfl_down(n_, off, 64);
                d_ += __shfl_down(d_, off, 64);
            }
            num[a][c] = n_; den[a][c] = d_;
        }

    __shared__ float s_num[4][TI * 3];
    __shared__ float s_den[4][TI * 3];
    const int lane = tid & 63, wave = tid >> 6;
    if (lane == 0) {
#pragma unroll
        for (int a = 0; a < TI; ++a)
#pragma unroll
            for (int c = 0; c < 3; ++c) {
                s_num[wave][a * 3 + c] = num[a][c];
                s_den[wave][a * 3 + c] = den[a][c];
            }
    }
    __syncthreads();

    if (tid < TI * 3) {
        float n_ = 0.f, d_ = 0.f;
#pragma unroll
        for (int w = 0; w < 4; ++w) { n_ += s_num[w][tid]; d_ += s_den[w][tid]; }
        const int a = tid / 3, c = tid - a * 3;
        const int i = i0 + a;
        // leave-one-out: subtract the j==i self term
        float dd  = Ft[3 * i + c] - Fx[3 * i + c];
        float kii = exp2f(scale * dd * dd);
        n_ -= kii * Y[3 * i + c];
        d_ -= kii;
        out[3 * i + c] = n_ / d_;
    }
}

extern "C" void kernel_launch(void* const* d_in, const int* in_sizes, int n_in,
                              void* d_out, int out_size, void* d_ws, size_t ws_size,
                              hipStream_t stream) {
    const float* x  = (const float*)d_in[0];  // [N,4]
    const float* tX = (const float*)d_in[1];  // [N,4]
    const float* Y  = (const float*)d_in[2];  // [N,3]
    const float* W  = (const float*)d_in[3];  // [3,4]
    const float* h  = (const float*)d_in[4];  // [1]

    const int N = in_sizes[0] / 4;
    float* F = (float*)d_ws;  // 2*N*3 floats (~98 KB)

    const int total = 2 * N;
    proj_kernel<<<(total + 255) / 256, 256, 0, stream>>>(x, tX, W, F, N);
    kde_main<<<N / TI, BLK, 0, stream>>>(F, Y, h, (float*)d_out, N);
}